// Round 1
// baseline (543.057 us; speedup 1.0000x reference)
//
#include <hip/hip_runtime.h>

#define B_ 2
#define T_ 4096
#define C_ 768
#define H_ 12
#define D_ 64

typedef __attribute__((ext_vector_type(8))) short bf16x8;
typedef __attribute__((ext_vector_type(4))) float f32x4;

__device__ __forceinline__ unsigned short f2bf(float f) {
  union { float f; unsigned u; } v; v.f = f;
  unsigned r = v.u + 0x7fffu + ((v.u >> 16) & 1u);
  return (unsigned short)(r >> 16);
}

__device__ __forceinline__ void gll16(const void* g, void* l) {
  __builtin_amdgcn_global_load_lds((const __attribute__((address_space(1))) void*)g,
                                   (__attribute__((address_space(3))) void*)l, 16, 0, 0);
}

// ---------------- cast kernels ----------------

__global__ __launch_bounds__(256) void cast_bf16_k(const float* __restrict__ in,
                                                   unsigned short* __restrict__ out, int n4) {
  int i = blockIdx.x * 256 + threadIdx.x;
  if (i >= n4) return;
  float4 v = ((const float4*)in)[i];
  union { unsigned short s[4]; unsigned long long u; } o;
  o.s[0] = f2bf(v.x); o.s[1] = f2bf(v.y); o.s[2] = f2bf(v.z); o.s[3] = f2bf(v.w);
  ((unsigned long long*)out)[i] = o.u;
}

// in [R][C] f32 -> out [C][R] bf16   (B^T layout for GEMM)
__global__ __launch_bounds__(256) void tcast_bf16_k(const float* __restrict__ in,
                                                    unsigned short* __restrict__ out,
                                                    int R, int C) {
  int idx = blockIdx.x * 256 + threadIdx.x;
  if (idx >= R * C) return;
  int r = idx / C, c = idx - r * C;
  out[(size_t)c * R + r] = f2bf(in[idx]);
}

// ---------------- GEMM: A[M][K] bf16 row-major, Bt[N][K] bf16 row-major ----------------
// 128x128 tile, BK=32, 4 waves (2x2), each wave 64x64 = 4x4 frags of 16x16x32 MFMA.
// LDS chunk swizzle: stored chunk cc holds global chunk c = cc ^ ((r>>1)&3)  (2-way reads = free)
// MODE 0: split-scatter epilogue into Q[B,H,T,D], K[B,H,T,D], Vt[B,H,D,T] (bf16)
// MODE 1: f32 out [M][768] + bias

template <int MODE>
__global__ __launch_bounds__(256) void gemm_k(const unsigned short* __restrict__ A,
                                              const unsigned short* __restrict__ Bt,
                                              int K,
                                              unsigned short* __restrict__ q_out,
                                              unsigned short* __restrict__ k_out,
                                              unsigned short* __restrict__ vt_out,
                                              float* __restrict__ f_out,
                                              const float* __restrict__ bias) {
  __shared__ short a_lds[128 * 32];
  __shared__ short b_lds[128 * 32];
  const int tid = threadIdx.x;
  const int wave = tid >> 6, lane = tid & 63;
  const int wm = wave >> 1, wn = wave & 1;
  const int lr = lane & 15, lc = lane >> 4;
  const int m0 = blockIdx.x * 128, n0 = blockIdx.y * 128;

  f32x4 acc[4][4];
  for (int mi = 0; mi < 4; ++mi)
    for (int ni = 0; ni < 4; ++ni) acc[mi][ni] = (f32x4){0.f, 0.f, 0.f, 0.f};

  for (int k0 = 0; k0 < K; k0 += 32) {
    __syncthreads();
    for (int p = 0; p < 2; ++p) {
      int chunk = p * 256 + wave * 64 + lane;
      int r = chunk >> 2, cc = chunk & 3;
      int c = cc ^ ((r >> 1) & 3);
      int base = (p * 256 + wave * 64) * 8;  // shorts; wave-uniform
      gll16(A + (size_t)(m0 + r) * K + k0 + c * 8, a_lds + base);
      gll16(Bt + (size_t)(n0 + r) * K + k0 + c * 8, b_lds + base);
    }
    __syncthreads();
    bf16x8 af[4], bfrag[4];
    for (int mi = 0; mi < 4; ++mi) {
      int r = wm * 64 + mi * 16 + lr;
      af[mi] = *(const bf16x8*)&a_lds[r * 32 + (lc ^ ((r >> 1) & 3)) * 8];
    }
    for (int ni = 0; ni < 4; ++ni) {
      int r = wn * 64 + ni * 16 + lr;
      bfrag[ni] = *(const bf16x8*)&b_lds[r * 32 + (lc ^ ((r >> 1) & 3)) * 8];
    }
    for (int mi = 0; mi < 4; ++mi)
      for (int ni = 0; ni < 4; ++ni)
        acc[mi][ni] = __builtin_amdgcn_mfma_f32_16x16x32_bf16(af[mi], bfrag[ni], acc[mi][ni], 0, 0, 0);
  }

  // epilogue. C/D layout: col = lane&15, row = (lane>>4)*4 + reg   [m89-verified]
  if (MODE == 0) {
    for (int mi = 0; mi < 4; ++mi)
      for (int ni = 0; ni < 4; ++ni) {
        int nn = n0 + wn * 64 + ni * 16 + lr;      // 0..2303
        int which = nn / 768;                      // uniform per block (128 | 768)
        int rem = nn - which * 768;
        int h = rem >> 6, d = rem & 63;
        for (int r = 0; r < 4; ++r) {
          int m = m0 + wm * 64 + mi * 16 + lc * 4 + r;
          int b = m >> 12, t = m & (T_ - 1);
          unsigned short val = f2bf(acc[mi][ni][r]);
          size_t bh = (size_t)(b * H_ + h);
          if (which == 0)      q_out[(bh * T_ + t) * D_ + d] = val;
          else if (which == 1) k_out[(bh * T_ + t) * D_ + d] = val;
          else                 vt_out[(bh * D_ + d) * T_ + t] = val;
        }
      }
  } else {
    for (int mi = 0; mi < 4; ++mi)
      for (int ni = 0; ni < 4; ++ni) {
        int nn = n0 + wn * 64 + ni * 16 + lr;
        float bv = bias[nn];
        for (int r = 0; r < 4; ++r) {
          int m = m0 + wm * 64 + mi * 16 + lc * 4 + r;
          f_out[(size_t)m * C_ + nn] = acc[mi][ni][r] + bv;
        }
      }
  }
}

// ---------------- flash attention ----------------
// grid: (T/64, B*H), 256 threads = 4 waves, wave w owns q rows [qbase+16w, +16).
// KV tile = 32 keys. K_lds [32][64] (chunk swz c^(r&7)), Vt_lds [64][32] (swz c^((d>>1)&3)).
__global__ __launch_bounds__(256) void flash_k(const unsigned short* __restrict__ Qg,
                                               const unsigned short* __restrict__ Kg,
                                               const unsigned short* __restrict__ Vtg,
                                               unsigned short* __restrict__ Og) {
  __shared__ short k_lds[32 * 64];
  __shared__ short vt_lds[64 * 32];
  __shared__ short p_lds[4][16 * 40];   // stride 40 breaks 8-way bank conflict

  const int tid = threadIdx.x;
  const int wave = tid >> 6, lane = tid & 63;
  const int lr = lane & 15, lc = lane >> 4;
  const int qbase = blockIdx.x * 64;
  const int bh = blockIdx.y;
  const int qw = qbase + wave * 16;

  // Q fragments (A-layout: row = lane&15, k = (lane>>4)*8 + j)
  const unsigned short* qrow = Qg + ((size_t)bh * T_ + qw + lr) * D_;
  bf16x8 qa0 = *(const bf16x8*)(qrow + lc * 8);
  bf16x8 qa1 = *(const bf16x8*)(qrow + 32 + lc * 8);

  float m_r[4], l_r[4];
  f32x4 accO[4];
  for (int r = 0; r < 4; ++r) { m_r[r] = -INFINITY; l_r[r] = 0.f; }
  for (int ni = 0; ni < 4; ++ni) accO[ni] = (f32x4){0.f, 0.f, 0.f, 0.f};

  const int ntiles = (qbase + 64) >> 5;
  for (int it = 0; it < ntiles; ++it) {
    const int kv = it << 5;
    __syncthreads();
    {
      int chunk = wave * 64 + lane;
      int r = chunk >> 3, cc = chunk & 7;           // K: 32 rows x 8 chunks
      int c = cc ^ (r & 7);
      gll16(Kg + ((size_t)bh * T_ + kv + r) * D_ + c * 8, k_lds + wave * 512);
      int d = chunk >> 2, c2 = chunk & 3;           // Vt: 64 rows x 4 chunks
      int cv = c2 ^ ((d >> 1) & 3);
      gll16(Vtg + ((size_t)bh * D_ + d) * T_ + kv + cv * 8, vt_lds + wave * 512);
    }
    __syncthreads();
    if (kv > qw + 15) continue;   // tile fully masked for this wave (barriers stay matched)

    // S = Q K^T  (B-frag of K^T == A-layout rows of K)
    f32x4 s[2];
    for (int kc = 0; kc < 2; ++kc) {
      int key = kc * 16 + lr;
      bf16x8 kb0 = *(const bf16x8*)&k_lds[(key * 8 + (lc ^ (key & 7))) * 8];
      bf16x8 kb1 = *(const bf16x8*)&k_lds[(key * 8 + ((lc + 4) ^ (key & 7))) * 8];
      f32x4 z = (f32x4){0.f, 0.f, 0.f, 0.f};
      z = __builtin_amdgcn_mfma_f32_16x16x32_bf16(qa0, kb0, z, 0, 0, 0);
      z = __builtin_amdgcn_mfma_f32_16x16x32_bf16(qa1, kb1, z, 0, 0, 0);
      s[kc] = z;
    }
    // scale + causal mask
    for (int kc = 0; kc < 2; ++kc)
      for (int r = 0; r < 4; ++r) {
        int keyg = kv + kc * 16 + lr;
        int qg = qw + lc * 4 + r;
        float sv = s[kc][r] * 0.125f;
        s[kc][r] = (keyg <= qg) ? sv : -INFINITY;
      }
    // row max over 16-lane column group
    float rx[4];
    for (int r = 0; r < 4; ++r) rx[r] = fmaxf(s[0][r], s[1][r]);
    for (int off = 1; off <= 8; off <<= 1)
      for (int r = 0; r < 4; ++r) rx[r] = fmaxf(rx[r], __shfl_xor(rx[r], off));
    float alpha[4];
    for (int r = 0; r < 4; ++r) {
      float mn = fmaxf(m_r[r], rx[r]);
      alpha[r] = __expf(m_r[r] - mn);
      m_r[r] = mn;
    }
    float ps[4];
    for (int r = 0; r < 4; ++r) {
      float p0 = __expf(s[0][r] - m_r[r]);
      float p1 = __expf(s[1][r] - m_r[r]);
      s[0][r] = p0; s[1][r] = p1;
      ps[r] = p0 + p1;
    }
    for (int off = 1; off <= 8; off <<= 1)
      for (int r = 0; r < 4; ++r) ps[r] += __shfl_xor(ps[r], off);
    for (int r = 0; r < 4; ++r) l_r[r] = l_r[r] * alpha[r] + ps[r];
    for (int ni = 0; ni < 4; ++ni)
      for (int r = 0; r < 4; ++r) accO[ni][r] *= alpha[r];

    // P (C-layout) -> per-wave LDS -> A-layout frag
    for (int kc = 0; kc < 2; ++kc)
      for (int r = 0; r < 4; ++r)
        p_lds[wave][(lc * 4 + r) * 40 + kc * 16 + lr] = (short)f2bf(s[kc][r]);
    bf16x8 pa = *(const bf16x8*)&p_lds[wave][lr * 40 + lc * 8];

    // O += P V   (B-frag from Vt_lds rows = contiguous b128)
    for (int ni = 0; ni < 4; ++ni) {
      int d = ni * 16 + lr;
      bf16x8 vb = *(const bf16x8*)&vt_lds[(d * 4 + (lc ^ ((d >> 1) & 3))) * 8];
      accO[ni] = __builtin_amdgcn_mfma_f32_16x16x32_bf16(pa, vb, accO[ni], 0, 0, 0);
    }
  }

  // epilogue -> attn_out [B][T][C] bf16
  const int b = bh / H_, h = bh - b * H_;
  for (int r = 0; r < 4; ++r) {
    float inv = 1.0f / l_r[r];
    int t = qw + lc * 4 + r;
    size_t o = ((size_t)b * T_ + t) * C_ + h * D_;
    for (int ni = 0; ni < 4; ++ni)
      Og[o + ni * 16 + lr] = f2bf(accO[ni][r] * inv);
  }
}

// ---------------- launcher ----------------

extern "C" void kernel_launch(void* const* d_in, const int* in_sizes, int n_in,
                              void* d_out, int out_size, void* d_ws, size_t ws_size,
                              hipStream_t stream) {
  const float* x     = (const float*)d_in[0];
  const float* Wqkv  = (const float*)d_in[1];
  const float* Wproj = (const float*)d_in[2];
  const float* bproj = (const float*)d_in[3];
  float* out = (float*)d_out;

  // workspace layout (bytes):
  //   [0, 12582912)            x_bf16  (reused as attn_out after GEMM1)
  //   [12582912, 16121856)     Wqkv^T bf16  [2304][768]
  //   [16121856, 17301504)     Wproj^T bf16 [768][768]
  //   [17301504, 29884416)     Q  [B,H,T,D] bf16
  //   [29884416, 42467328)     K  [B,H,T,D] bf16
  //   [42467328, 55050240)     Vt [B,H,D,T] bf16
  char* ws = (char*)d_ws;
  unsigned short* xbf   = (unsigned short*)(ws);
  unsigned short* wqkvt = (unsigned short*)(ws + 12582912);
  unsigned short* wprjt = (unsigned short*)(ws + 16121856);
  unsigned short* Qb    = (unsigned short*)(ws + 17301504);
  unsigned short* Kb    = (unsigned short*)(ws + 29884416);
  unsigned short* Vtb   = (unsigned short*)(ws + 42467328);

  cast_bf16_k<<<6144, 256, 0, stream>>>(x, xbf, (B_ * T_ * C_) / 4);
  tcast_bf16_k<<<(C_ * 3 * C_) / 256, 256, 0, stream>>>(Wqkv, wqkvt, C_, 3 * C_);
  tcast_bf16_k<<<(C_ * C_) / 256, 256, 0, stream>>>(Wproj, wprjt, C_, C_);

  gemm_k<0><<<dim3((B_ * T_) / 128, (3 * C_) / 128), 256, 0, stream>>>(
      xbf, wqkvt, C_, Qb, Kb, Vtb, nullptr, nullptr);

  flash_k<<<dim3(T_ / 64, B_ * H_), 256, 0, stream>>>(Qb, Kb, Vtb, xbf);

  gemm_k<1><<<dim3((B_ * T_) / 128, C_ / 128), 256, 0, stream>>>(
      xbf, wprjt, C_, nullptr, nullptr, nullptr, out, bproj);
}

// Round 2
// 262.022 us; speedup vs baseline: 2.0726x; 2.0726x over previous
//
#include <hip/hip_runtime.h>

#define B_ 2
#define T_ 4096
#define C_ 768
#define H_ 12
#define D_ 64

typedef __attribute__((ext_vector_type(8))) short bf16x8;
typedef __attribute__((ext_vector_type(4))) float f32x4;
typedef __attribute__((ext_vector_type(16))) float f32x16;
typedef unsigned short ushort_t;

__device__ __forceinline__ unsigned short f2bf(float f) {
  union { float f; unsigned u; } v; v.f = f;
  unsigned r = v.u + 0x7fffu + ((v.u >> 16) & 1u);
  return (unsigned short)(r >> 16);
}

__device__ __forceinline__ float exp2_hw(float x) {
  float r;
  asm("v_exp_f32 %0, %1" : "=v"(r) : "v"(x));
  return r;
}

__device__ __forceinline__ void gll16(const void* g, void* l) {
  __builtin_amdgcn_global_load_lds((const __attribute__((address_space(1))) void*)g,
                                   (__attribute__((address_space(3))) void*)l, 16, 0, 0);
}

// ---------------- cast kernels ----------------

__global__ __launch_bounds__(256) void cast_bf16_k(const float* __restrict__ in,
                                                   unsigned short* __restrict__ out, int n4) {
  int i = blockIdx.x * 256 + threadIdx.x;
  if (i >= n4) return;
  float4 v = ((const float4*)in)[i];
  union { unsigned short s[4]; unsigned long long u; } o;
  o.s[0] = f2bf(v.x); o.s[1] = f2bf(v.y); o.s[2] = f2bf(v.z); o.s[3] = f2bf(v.w);
  ((unsigned long long*)out)[i] = o.u;
}

// in [R][C] f32 -> out [C][R] bf16   (B^T layout for GEMM)
__global__ __launch_bounds__(256) void tcast_bf16_k(const float* __restrict__ in,
                                                    unsigned short* __restrict__ out,
                                                    int R, int C) {
  int idx = blockIdx.x * 256 + threadIdx.x;
  if (idx >= R * C) return;
  int r = idx / C, c = idx - r * C;
  out[(size_t)c * R + r] = f2bf(in[idx]);
}

// ---------------- GEMM: A[M][K] bf16 row-major, Bt[N][K] bf16 row-major ----------------
// 128x128 tile, BK=32, 4 waves (2x2). MODE 0: scatter into Q(scaled)/K/Vt. MODE 1: f32 + bias.

#define QSCALE 0.1803368801111243f  /* 0.125 * log2(e) */

template <int MODE>
__global__ __launch_bounds__(256) void gemm_k(const unsigned short* __restrict__ A,
                                              const unsigned short* __restrict__ Bt,
                                              int K,
                                              unsigned short* __restrict__ q_out,
                                              unsigned short* __restrict__ k_out,
                                              unsigned short* __restrict__ vt_out,
                                              float* __restrict__ f_out,
                                              const float* __restrict__ bias) {
  __shared__ short a_lds[128 * 32];
  __shared__ short b_lds[128 * 32];
  const int tid = threadIdx.x;
  const int wave = tid >> 6, lane = tid & 63;
  const int wm = wave >> 1, wn = wave & 1;
  const int lr = lane & 15, lc = lane >> 4;
  const int m0 = blockIdx.x * 128, n0 = blockIdx.y * 128;

  f32x4 acc[4][4];
  for (int mi = 0; mi < 4; ++mi)
    for (int ni = 0; ni < 4; ++ni) acc[mi][ni] = (f32x4){0.f, 0.f, 0.f, 0.f};

  for (int k0 = 0; k0 < K; k0 += 32) {
    __syncthreads();
    for (int p = 0; p < 2; ++p) {
      int chunk = p * 256 + wave * 64 + lane;
      int r = chunk >> 2, cc = chunk & 3;
      int c = cc ^ ((r >> 1) & 3);
      int base = (p * 256 + wave * 64) * 8;
      gll16(A + (size_t)(m0 + r) * K + k0 + c * 8, a_lds + base);
      gll16(Bt + (size_t)(n0 + r) * K + k0 + c * 8, b_lds + base);
    }
    __syncthreads();
    bf16x8 af[4], bfrag[4];
    for (int mi = 0; mi < 4; ++mi) {
      int r = wm * 64 + mi * 16 + lr;
      af[mi] = *(const bf16x8*)&a_lds[r * 32 + (lc ^ ((r >> 1) & 3)) * 8];
    }
    for (int ni = 0; ni < 4; ++ni) {
      int r = wn * 64 + ni * 16 + lr;
      bfrag[ni] = *(const bf16x8*)&b_lds[r * 32 + (lc ^ ((r >> 1) & 3)) * 8];
    }
    for (int mi = 0; mi < 4; ++mi)
      for (int ni = 0; ni < 4; ++ni)
        acc[mi][ni] = __builtin_amdgcn_mfma_f32_16x16x32_bf16(af[mi], bfrag[ni], acc[mi][ni], 0, 0, 0);
  }

  if (MODE == 0) {
    for (int mi = 0; mi < 4; ++mi)
      for (int ni = 0; ni < 4; ++ni) {
        int nn = n0 + wn * 64 + ni * 16 + lr;
        int which = nn / 768;
        int rem = nn - which * 768;
        int h = rem >> 6, d = rem & 63;
        for (int r = 0; r < 4; ++r) {
          int m = m0 + wm * 64 + mi * 16 + lc * 4 + r;
          int b = m >> 12, t = m & (T_ - 1);
          float av = acc[mi][ni][r];
          if (which == 0) av *= QSCALE;   // fold softmax scale + log2e into Q
          unsigned short val = f2bf(av);
          size_t bh = (size_t)(b * H_ + h);
          if (which == 0)      q_out[(bh * T_ + t) * D_ + d] = val;
          else if (which == 1) k_out[(bh * T_ + t) * D_ + d] = val;
          else                 vt_out[(bh * D_ + d) * T_ + t] = val;
        }
      }
  } else {
    for (int mi = 0; mi < 4; ++mi)
      for (int ni = 0; ni < 4; ++ni) {
        int nn = n0 + wn * 64 + ni * 16 + lr;
        float bv = bias[nn];
        for (int r = 0; r < 4; ++r) {
          int m = m0 + wm * 64 + mi * 16 + lc * 4 + r;
          f_out[(size_t)m * C_ + nn] = acc[mi][ni][r] + bv;
        }
      }
  }
}

// ---------------- flash attention v2 (swapped 32x32 MFMA, register softmax) ----------------
// grid: 768 blocks 1D. 4 waves; wave owns 32 q rows; KV tile = 64, double-buffered.
// QK^T: mfma(A=K, B=Q) -> S^T, lane = one q col, 32 keys in regs.
// PV:   mfma(A=Vt, B=P^T) -> O^T, lane = one q col, 64 d in regs (2 acc tiles).

#define PACK8(SV, O)                                                              \
  do {                                                                            \
    unsigned w0, w1, w2, w3, w4, w5, w6, w7;                                      \
    asm("v_cvt_pk_bf16_f32 %0, %1, %2" : "=v"(w0) : "v"(SV[0]), "v"(SV[1]));      \
    asm("v_cvt_pk_bf16_f32 %0, %1, %2" : "=v"(w1) : "v"(SV[2]), "v"(SV[3]));      \
    asm("v_cvt_pk_bf16_f32 %0, %1, %2" : "=v"(w2) : "v"(SV[4]), "v"(SV[5]));      \
    asm("v_cvt_pk_bf16_f32 %0, %1, %2" : "=v"(w3) : "v"(SV[6]), "v"(SV[7]));      \
    asm("v_cvt_pk_bf16_f32 %0, %1, %2" : "=v"(w4) : "v"(SV[8]), "v"(SV[9]));      \
    asm("v_cvt_pk_bf16_f32 %0, %1, %2" : "=v"(w5) : "v"(SV[10]), "v"(SV[11]));    \
    asm("v_cvt_pk_bf16_f32 %0, %1, %2" : "=v"(w6) : "v"(SV[12]), "v"(SV[13]));    \
    asm("v_cvt_pk_bf16_f32 %0, %1, %2" : "=v"(w7) : "v"(SV[14]), "v"(SV[15]));    \
    asm("v_permlane32_swap_b32 %0, %1" : "+v"(w0), "+v"(w2));                     \
    asm("v_permlane32_swap_b32 %0, %1" : "+v"(w1), "+v"(w3));                     \
    asm("v_permlane32_swap_b32 %0, %1" : "+v"(w4), "+v"(w6));                     \
    asm("v_permlane32_swap_b32 %0, %1" : "+v"(w5), "+v"(w7));                     \
    pw[(O) + 0] = w0; pw[(O) + 1] = w1; pw[(O) + 2] = w2; pw[(O) + 3] = w3;       \
    pw[(O) + 4] = w4; pw[(O) + 5] = w5; pw[(O) + 6] = w6; pw[(O) + 7] = w7;       \
  } while (0)

__global__ __launch_bounds__(256) void flash2_k(const unsigned short* __restrict__ Qg,
                                                const unsigned short* __restrict__ Kg,
                                                const unsigned short* __restrict__ Vtg,
                                                unsigned short* __restrict__ Og) {
  __shared__ short k_lds[2][64 * 64];
  __shared__ short vt_lds[2][64 * 64];

  const int tid = threadIdx.x;
  const int wave = tid >> 6, lane = tid & 63;
  const int lq = lane & 31, hi = lane >> 5;

  // XCD-aware swizzle: same-bh blocks share an XCD L2; qi pairing balances load.
  const int id = blockIdx.x;
  const int xcd = id & 7, idx = id >> 3;
  const int bh = (idx >> 5) * 8 + xcd;
  const int xq = idx & 31;
  const int qi = (xq & 1) ? (31 - (xq >> 1)) : (xq >> 1);
  const int q0 = qi * 128;
  const int qw = q0 + wave * 32;
  const int q_g = qw + lq;

  // Q B-frags (col=q=lane&31, k(d) = hi*8+j), pre-scaled by 0.125*log2e in GEMM1
  const unsigned short* qrow = Qg + ((size_t)bh * T_ + q_g) * D_;
  bf16x8 qf[4];
#pragma unroll
  for (int t = 0; t < 4; ++t) qf[t] = *(const bf16x8*)(qrow + t * 16 + hi * 8);

  f32x16 accT0, accT1;
#pragma unroll
  for (int r = 0; r < 16; ++r) { accT0[r] = 0.f; accT1[r] = 0.f; }
  float m = -INFINITY, l = 0.f;

  const int nt = 2 * qi + 2;

  const size_t kbase = (size_t)bh * T_ * D_;
  const size_t vbase = (size_t)bh * D_ * T_;

  // stage tile 'it' into buffer 'buf'
  auto stage = [&](int it, int buf) {
    const int kv = it * 64;
#pragma unroll
    for (int p = 0; p < 2; ++p) {
      int ch = p * 256 + tid;
      int row = ch >> 3, cs = ch & 7;
      int c = cs ^ (row & 7);
      short* kd = &k_lds[buf][(p * 256 + wave * 64) * 8];
      short* vd = &vt_lds[buf][(p * 256 + wave * 64) * 8];
      gll16(Kg + kbase + (size_t)(kv + row) * D_ + c * 8, kd);
      gll16(Vtg + vbase + (size_t)row * T_ + kv + c * 8, vd);
    }
  };

  stage(0, 0);
  __syncthreads();

  for (int it = 0; it < nt; ++it) {
    const int kv = it * 64;
    const int buf = it & 1;
    if (it + 1 < nt) stage(it + 1, buf ^ 1);

    if (kv <= qw + 31) {  // not fully masked for this wave
      // ---- S^T = K Q^T ----
      f32x16 s0, s1;
#pragma unroll
      for (int r = 0; r < 16; ++r) { s0[r] = 0.f; s1[r] = 0.f; }
#pragma unroll
      for (int t = 0; t < 4; ++t) {
        bf16x8 kf = *(const bf16x8*)&k_lds[buf][lq * 64 + ((2 * t + hi) ^ (lq & 7)) * 8];
        s0 = __builtin_amdgcn_mfma_f32_32x32x16_bf16(kf, qf[t], s0, 0, 0, 0);
      }
#pragma unroll
      for (int t = 0; t < 4; ++t) {
        int key = 32 + lq;
        bf16x8 kf = *(const bf16x8*)&k_lds[buf][key * 64 + ((2 * t + hi) ^ (key & 7)) * 8];
        s1 = __builtin_amdgcn_mfma_f32_32x32x16_bf16(kf, qf[t], s1, 0, 0, 0);
      }

      // ---- causal mask (diagonal tiles only) ----
      if (kv + 63 > qw) {
#pragma unroll
        for (int r = 0; r < 16; ++r) {
          int key0 = kv + ((r & 3) + 8 * (r >> 2) + 4 * hi);
          if (key0 > q_g) s0[r] = -INFINITY;
          if (key0 + 32 > q_g) s1[r] = -INFINITY;
        }
      }

      // ---- online softmax (register-local; log2 domain) ----
      float rx = s0[0];
#pragma unroll
      for (int r = 1; r < 16; ++r) rx = fmaxf(rx, s0[r]);
#pragma unroll
      for (int r = 0; r < 16; ++r) rx = fmaxf(rx, s1[r]);
      rx = fmaxf(rx, __shfl_xor(rx, 32));
      float mn = fmaxf(m, rx);
      float al = exp2_hw(m - mn);
      m = mn;
      float sum = 0.f;
#pragma unroll
      for (int r = 0; r < 16; ++r) { s0[r] = exp2_hw(s0[r] - mn); sum += s0[r]; }
#pragma unroll
      for (int r = 0; r < 16; ++r) { s1[r] = exp2_hw(s1[r] - mn); sum += s1[r]; }
      sum += __shfl_xor(sum, 32);
      l = l * al + sum;
#pragma unroll
      for (int r = 0; r < 16; ++r) { accT0[r] *= al; accT1[r] *= al; }

      // ---- P^T -> bf16 B-frags via cvt_pk + permlane32_swap ----
      unsigned pw[16];
      PACK8(s0, 0);
      PACK8(s1, 8);

      // ---- O^T += Vt P^T ----
#pragma unroll
      for (int ks = 0; ks < 4; ++ks) {
        union { unsigned u[4]; bf16x8 v; } pb;
        pb.u[0] = pw[ks * 4 + 0]; pb.u[1] = pw[ks * 4 + 1];
        pb.u[2] = pw[ks * 4 + 2]; pb.u[3] = pw[ks * 4 + 3];
        bf16x8 vf0 = *(const bf16x8*)&vt_lds[buf][lq * 64 + ((2 * ks + hi) ^ (lq & 7)) * 8];
        accT0 = __builtin_amdgcn_mfma_f32_32x32x16_bf16(vf0, pb.v, accT0, 0, 0, 0);
        int d1 = 32 + lq;
        bf16x8 vf1 = *(const bf16x8*)&vt_lds[buf][d1 * 64 + ((2 * ks + hi) ^ (d1 & 7)) * 8];
        accT1 = __builtin_amdgcn_mfma_f32_32x32x16_bf16(vf1, pb.v, accT1, 0, 0, 0);
      }
    }
    __syncthreads();
  }

  // ---- epilogue: O^T cols are lane-local; write [B][T][C] bf16 ----
  const float inv = 1.0f / l;
  const int b = bh / H_, h = bh - b * H_;
  unsigned short* orow = Og + ((size_t)b * T_ + q_g) * C_ + h * D_;
#pragma unroll
  for (int g = 0; g < 4; ++g) {
    int d0 = 8 * g + 4 * hi;
    unsigned u0 = (unsigned)f2bf(accT0[4 * g + 0] * inv) | ((unsigned)f2bf(accT0[4 * g + 1] * inv) << 16);
    unsigned u1 = (unsigned)f2bf(accT0[4 * g + 2] * inv) | ((unsigned)f2bf(accT0[4 * g + 3] * inv) << 16);
    *(unsigned*)(orow + d0) = u0;
    *(unsigned*)(orow + d0 + 2) = u1;
    unsigned u2 = (unsigned)f2bf(accT1[4 * g + 0] * inv) | ((unsigned)f2bf(accT1[4 * g + 1] * inv) << 16);
    unsigned u3 = (unsigned)f2bf(accT1[4 * g + 2] * inv) | ((unsigned)f2bf(accT1[4 * g + 3] * inv) << 16);
    *(unsigned*)(orow + 32 + d0) = u2;
    *(unsigned*)(orow + 32 + d0 + 2) = u3;
  }
}

// ---------------- launcher ----------------

extern "C" void kernel_launch(void* const* d_in, const int* in_sizes, int n_in,
                              void* d_out, int out_size, void* d_ws, size_t ws_size,
                              hipStream_t stream) {
  const float* x     = (const float*)d_in[0];
  const float* Wqkv  = (const float*)d_in[1];
  const float* Wproj = (const float*)d_in[2];
  const float* bproj = (const float*)d_in[3];
  float* out = (float*)d_out;

  char* ws = (char*)d_ws;
  unsigned short* xbf   = (unsigned short*)(ws);
  unsigned short* wqkvt = (unsigned short*)(ws + 12582912);
  unsigned short* wprjt = (unsigned short*)(ws + 16121856);
  unsigned short* Qb    = (unsigned short*)(ws + 17301504);
  unsigned short* Kb    = (unsigned short*)(ws + 29884416);
  unsigned short* Vtb   = (unsigned short*)(ws + 42467328);

  cast_bf16_k<<<6144, 256, 0, stream>>>(x, xbf, (B_ * T_ * C_) / 4);
  tcast_bf16_k<<<(C_ * 3 * C_) / 256, 256, 0, stream>>>(Wqkv, wqkvt, C_, 3 * C_);
  tcast_bf16_k<<<(C_ * C_) / 256, 256, 0, stream>>>(Wproj, wprjt, C_, C_);

  gemm_k<0><<<dim3((B_ * T_) / 128, (3 * C_) / 128), 256, 0, stream>>>(
      xbf, wqkvt, C_, Qb, Kb, Vtb, nullptr, nullptr);

  flash2_k<<<768, 256, 0, stream>>>(Qb, Kb, Vtb, xbf);

  gemm_k<1><<<dim3((B_ * T_) / 128, C_ / 128), 256, 0, stream>>>(
      xbf, wprjt, C_, nullptr, nullptr, nullptr, out, bproj);
}

// Round 3
// 232.068 us; speedup vs baseline: 2.3401x; 1.1291x over previous
//
#include <hip/hip_runtime.h>

#define B_ 2
#define T_ 4096
#define C_ 768
#define H_ 12
#define D_ 64
#define NTASK 768  /* 24 bh * 32 q-tiles of 128 */

typedef __attribute__((ext_vector_type(8))) short bf16x8;
typedef __attribute__((ext_vector_type(4))) float f32x4;
typedef __attribute__((ext_vector_type(16))) float f32x16;

__device__ __forceinline__ unsigned short f2bf(float f) {
  union { float f; unsigned u; } v; v.f = f;
  unsigned r = v.u + 0x7fffu + ((v.u >> 16) & 1u);
  return (unsigned short)(r >> 16);
}

__device__ __forceinline__ float exp2_hw(float x) {
  float r;
  asm("v_exp_f32 %0, %1" : "=v"(r) : "v"(x));
  return r;
}

__device__ __forceinline__ void gll16(const void* g, void* l) {
  __builtin_amdgcn_global_load_lds((const __attribute__((address_space(1))) void*)g,
                                   (__attribute__((address_space(3))) void*)l, 16, 0, 0);
}

// ---------------- cast kernels ----------------

__global__ __launch_bounds__(256) void cast_bf16_k(const float* __restrict__ in,
                                                   unsigned short* __restrict__ out, int n4) {
  int i = blockIdx.x * 256 + threadIdx.x;
  if (i >= n4) return;
  float4 v = ((const float4*)in)[i];
  union { unsigned short s[4]; unsigned long long u; } o;
  o.s[0] = f2bf(v.x); o.s[1] = f2bf(v.y); o.s[2] = f2bf(v.z); o.s[3] = f2bf(v.w);
  ((unsigned long long*)out)[i] = o.u;
}

// in [R][C] f32 -> out [C][R] bf16; optionally resets the task counter
__global__ __launch_bounds__(256) void tcast_bf16_k(const float* __restrict__ in,
                                                    unsigned short* __restrict__ out,
                                                    int R, int C, unsigned* cnt) {
  int idx = blockIdx.x * 256 + threadIdx.x;
  if (cnt != nullptr && idx == 0) *cnt = 0u;
  if (idx >= R * C) return;
  int r = idx / C, c = idx - r * C;
  out[(size_t)c * R + r] = f2bf(in[idx]);
}

// ---------------- GEMM: A[M][K] bf16 row-major, Bt[N][K] bf16 row-major ----------------

#define QSCALE 0.1803368801111243f /* 0.125 * log2(e) */

template <int MODE>
__global__ __launch_bounds__(256) void gemm_k(const unsigned short* __restrict__ A,
                                              const unsigned short* __restrict__ Bt,
                                              int K,
                                              unsigned short* __restrict__ q_out,
                                              unsigned short* __restrict__ k_out,
                                              unsigned short* __restrict__ vt_out,
                                              float* __restrict__ f_out,
                                              const float* __restrict__ bias) {
  __shared__ short a_lds[128 * 32];
  __shared__ short b_lds[128 * 32];
  const int tid = threadIdx.x;
  const int wave = tid >> 6, lane = tid & 63;
  const int wm = wave >> 1, wn = wave & 1;
  const int lr = lane & 15, lc = lane >> 4;
  const int m0 = blockIdx.x * 128, n0 = blockIdx.y * 128;

  f32x4 acc[4][4];
  for (int mi = 0; mi < 4; ++mi)
    for (int ni = 0; ni < 4; ++ni) acc[mi][ni] = (f32x4){0.f, 0.f, 0.f, 0.f};

  for (int k0 = 0; k0 < K; k0 += 32) {
    __syncthreads();
    for (int p = 0; p < 2; ++p) {
      int chunk = p * 256 + wave * 64 + lane;
      int r = chunk >> 2, cc = chunk & 3;
      int c = cc ^ ((r >> 1) & 3);
      int base = (p * 256 + wave * 64) * 8;
      gll16(A + (size_t)(m0 + r) * K + k0 + c * 8, a_lds + base);
      gll16(Bt + (size_t)(n0 + r) * K + k0 + c * 8, b_lds + base);
    }
    __syncthreads();
    bf16x8 af[4], bfrag[4];
    for (int mi = 0; mi < 4; ++mi) {
      int r = wm * 64 + mi * 16 + lr;
      af[mi] = *(const bf16x8*)&a_lds[r * 32 + (lc ^ ((r >> 1) & 3)) * 8];
    }
    for (int ni = 0; ni < 4; ++ni) {
      int r = wn * 64 + ni * 16 + lr;
      bfrag[ni] = *(const bf16x8*)&b_lds[r * 32 + (lc ^ ((r >> 1) & 3)) * 8];
    }
    for (int mi = 0; mi < 4; ++mi)
      for (int ni = 0; ni < 4; ++ni)
        acc[mi][ni] = __builtin_amdgcn_mfma_f32_16x16x32_bf16(af[mi], bfrag[ni], acc[mi][ni], 0, 0, 0);
  }

  if (MODE == 0) {
    for (int mi = 0; mi < 4; ++mi)
      for (int ni = 0; ni < 4; ++ni) {
        int nn = n0 + wn * 64 + ni * 16 + lr;
        int which = nn / 768;
        int rem = nn - which * 768;
        int h = rem >> 6, d = rem & 63;
        for (int r = 0; r < 4; ++r) {
          int m = m0 + wm * 64 + mi * 16 + lc * 4 + r;
          int b = m >> 12, t = m & (T_ - 1);
          float av = acc[mi][ni][r];
          if (which == 0) av *= QSCALE;
          unsigned short val = f2bf(av);
          size_t bh = (size_t)(b * H_ + h);
          if (which == 0)      q_out[(bh * T_ + t) * D_ + d] = val;
          else if (which == 1) k_out[(bh * T_ + t) * D_ + d] = val;
          else                 vt_out[(bh * D_ + d) * T_ + t] = val;
        }
      }
  } else {
    for (int mi = 0; mi < 4; ++mi)
      for (int ni = 0; ni < 4; ++ni) {
        int nn = n0 + wn * 64 + ni * 16 + lr;
        float bv = bias[nn];
        for (int r = 0; r < 4; ++r) {
          int m = m0 + wm * 64 + mi * 16 + lc * 4 + r;
          f_out[(size_t)m * C_ + nn] = acc[mi][ni][r] + bv;
        }
      }
  }
}

// ---------------- flash attention v3 ----------------
// Persistent task queue (LPT order, heavy qi first). 512 blocks, 4 waves.
// Task = (bh, qi): 128 q rows, wave owns 32. KV tile = 64 keys, double-buffered.
// LDS holds MFMA fragments contiguously: frag f is 1KB at f*512 shorts, read at
// base + lane*16B  -> lane-linear ds_read_b128, zero bank conflicts by construction.
// K frag f=(t,half):  lane l holds K[half*32+(l&31)][t*16+(l>>5)*8 ..+8]
// V frag f=(ks,dh):   lane l holds Vt[dh*32+(l&31)][kv+ks*16+(l>>5)*8 ..+8]

#define PACK8(SV, O)                                                              \
  do {                                                                            \
    unsigned w0, w1, w2, w3, w4, w5, w6, w7;                                      \
    asm("v_cvt_pk_bf16_f32 %0, %1, %2" : "=v"(w0) : "v"(SV[0]), "v"(SV[1]));      \
    asm("v_cvt_pk_bf16_f32 %0, %1, %2" : "=v"(w1) : "v"(SV[2]), "v"(SV[3]));      \
    asm("v_cvt_pk_bf16_f32 %0, %1, %2" : "=v"(w2) : "v"(SV[4]), "v"(SV[5]));      \
    asm("v_cvt_pk_bf16_f32 %0, %1, %2" : "=v"(w3) : "v"(SV[6]), "v"(SV[7]));      \
    asm("v_cvt_pk_bf16_f32 %0, %1, %2" : "=v"(w4) : "v"(SV[8]), "v"(SV[9]));      \
    asm("v_cvt_pk_bf16_f32 %0, %1, %2" : "=v"(w5) : "v"(SV[10]), "v"(SV[11]));    \
    asm("v_cvt_pk_bf16_f32 %0, %1, %2" : "=v"(w6) : "v"(SV[12]), "v"(SV[13]));    \
    asm("v_cvt_pk_bf16_f32 %0, %1, %2" : "=v"(w7) : "v"(SV[14]), "v"(SV[15]));    \
    asm("v_permlane32_swap_b32 %0, %1" : "+v"(w0), "+v"(w2));                     \
    asm("v_permlane32_swap_b32 %0, %1" : "+v"(w1), "+v"(w3));                     \
    asm("v_permlane32_swap_b32 %0, %1" : "+v"(w4), "+v"(w6));                     \
    asm("v_permlane32_swap_b32 %0, %1" : "+v"(w5), "+v"(w7));                     \
    pw[(O) + 0] = w0; pw[(O) + 1] = w1; pw[(O) + 2] = w2; pw[(O) + 3] = w3;       \
    pw[(O) + 4] = w4; pw[(O) + 5] = w5; pw[(O) + 6] = w6; pw[(O) + 7] = w7;       \
  } while (0)

__global__ __launch_bounds__(256) void flash3_k(const unsigned short* __restrict__ Qg,
                                                const unsigned short* __restrict__ Kg,
                                                const unsigned short* __restrict__ Vtg,
                                                unsigned short* __restrict__ Og,
                                                unsigned* __restrict__ cnt) {
  __shared__ short k_lds[2][8 * 512];
  __shared__ short vt_lds[2][8 * 512];
  __shared__ int task_s;

  const int tid = threadIdx.x;
  const int wave = tid >> 6, lane = tid & 63;
  const int lq = lane & 31;

  for (;;) {
    if (tid == 0) task_s = (int)atomicAdd(cnt, 1u);
    __syncthreads();
    const int task = task_s;
    if (task >= NTASK) return;

    const int qi = 31 - (task / 24);  // LPT: heavy first
    const int bh = task - (task / 24) * 24;
    const int q0 = qi * 128;
    const int qw = q0 + wave * 32;
    const int q_g = qw + lq;

    const size_t kbase = (size_t)bh * T_ * D_;
    const size_t vbase = (size_t)bh * D_ * T_;

    // Q B-frags (pre-scaled by 0.125*log2e in GEMM1)
    const unsigned short* qrow = Qg + kbase + (size_t)q_g * D_;  // same layout as K
    bf16x8 qf[4];
#pragma unroll
    for (int t = 0; t < 4; ++t) qf[t] = *(const bf16x8*)(qrow + t * 16 + (lane >> 5) * 8);

    f32x16 accT0, accT1;
#pragma unroll
    for (int r = 0; r < 16; ++r) { accT0[r] = 0.f; accT1[r] = 0.f; }
    float m = -INFINITY, l = 0.f;

    const int nt = 2 * qi + 2;

    auto stage = [&](int it, int buf) {
      const int kv = it * 64;
#pragma unroll
      for (int p = 0; p < 2; ++p) {
        int f = p * 4 + wave;
        int th = f >> 1, hf = f & 1;  // K frag: (t, half)
        gll16(Kg + kbase + (size_t)(kv + hf * 32 + lq) * D_ + th * 16 + (lane >> 5) * 8,
              &k_lds[buf][f * 512]);
        gll16(Vtg + vbase + (size_t)(hf * 32 + lq) * T_ + kv + th * 16 + (lane >> 5) * 8,
              &vt_lds[buf][f * 512]);
      }
    };

    stage(0, 0);
    __syncthreads();

    for (int it = 0; it < nt; ++it) {
      const int kv = it * 64;
      const int buf = it & 1;
      if (it + 1 < nt) stage(it + 1, buf ^ 1);

      if (kv <= qw + 31) {
        // ---- S^T = K Q^T : lane = q col, 32 keys in regs (2 halves) ----
        f32x16 s0, s1;
#pragma unroll
        for (int r = 0; r < 16; ++r) { s0[r] = 0.f; s1[r] = 0.f; }
        __builtin_amdgcn_s_setprio(1);
#pragma unroll
        for (int t = 0; t < 4; ++t) {
          bf16x8 kf0 = *(const bf16x8*)&k_lds[buf][(t * 2 + 0) * 512 + lane * 8];
          bf16x8 kf1 = *(const bf16x8*)&k_lds[buf][(t * 2 + 1) * 512 + lane * 8];
          s0 = __builtin_amdgcn_mfma_f32_32x32x16_bf16(kf0, qf[t], s0, 0, 0, 0);
          s1 = __builtin_amdgcn_mfma_f32_32x32x16_bf16(kf1, qf[t], s1, 0, 0, 0);
        }
        __builtin_amdgcn_s_setprio(0);

        const int hi = lane >> 5;
        // ---- causal mask (diagonal tiles only) ----
        if (kv + 63 > qw) {
#pragma unroll
          for (int r = 0; r < 16; ++r) {
            int key0 = kv + ((r & 3) + 8 * (r >> 2) + 4 * hi);
            if (key0 > q_g) s0[r] = -INFINITY;
            if (key0 + 32 > q_g) s1[r] = -INFINITY;
          }
        }

        // ---- online softmax, log2 domain, defer-max (T13) ----
        float rx = fmaxf(s0[0], s0[1]);
#pragma unroll
        for (int r = 2; r < 16; ++r) rx = fmaxf(rx, s0[r]);
#pragma unroll
        for (int r = 0; r < 16; ++r) rx = fmaxf(rx, s1[r]);
        rx = fmaxf(rx, __shfl_xor(rx, 32));
        if (!__all(rx <= m + 8.f)) {
          float mn = fmaxf(m, rx);
          float al = exp2_hw(m - mn);
          m = mn;
          l *= al;
#pragma unroll
          for (int r = 0; r < 16; ++r) { accT0[r] *= al; accT1[r] *= al; }
        }
        float sum = 0.f;
#pragma unroll
        for (int r = 0; r < 16; ++r) { s0[r] = exp2_hw(s0[r] - m); sum += s0[r]; }
#pragma unroll
        for (int r = 0; r < 16; ++r) { s1[r] = exp2_hw(s1[r] - m); sum += s1[r]; }
        sum += __shfl_xor(sum, 32);
        l += sum;

        // ---- P^T -> bf16 B-frags ----
        unsigned pw[16];
        PACK8(s0, 0);
        PACK8(s1, 8);

        // ---- O^T += Vt P^T ----
        __builtin_amdgcn_s_setprio(1);
#pragma unroll
        for (int ks = 0; ks < 4; ++ks) {
          union { unsigned u[4]; bf16x8 v; } pb;
          pb.u[0] = pw[ks * 4 + 0]; pb.u[1] = pw[ks * 4 + 1];
          pb.u[2] = pw[ks * 4 + 2]; pb.u[3] = pw[ks * 4 + 3];
          bf16x8 vf0 = *(const bf16x8*)&vt_lds[buf][(ks * 2 + 0) * 512 + lane * 8];
          bf16x8 vf1 = *(const bf16x8*)&vt_lds[buf][(ks * 2 + 1) * 512 + lane * 8];
          accT0 = __builtin_amdgcn_mfma_f32_32x32x16_bf16(vf0, pb.v, accT0, 0, 0, 0);
          accT1 = __builtin_amdgcn_mfma_f32_32x32x16_bf16(vf1, pb.v, accT1, 0, 0, 0);
        }
        __builtin_amdgcn_s_setprio(0);
      }
      __syncthreads();
    }

    // ---- epilogue ----
    const float inv = 1.0f / l;
    const int b = bh / H_, h = bh - b * H_;
    const int hi = lane >> 5;
    unsigned short* orow = Og + ((size_t)b * T_ + q_g) * C_ + h * D_;
#pragma unroll
    for (int g = 0; g < 4; ++g) {
      int d0 = 8 * g + 4 * hi;
      unsigned u0 = (unsigned)f2bf(accT0[4 * g + 0] * inv) | ((unsigned)f2bf(accT0[4 * g + 1] * inv) << 16);
      unsigned u1 = (unsigned)f2bf(accT0[4 * g + 2] * inv) | ((unsigned)f2bf(accT0[4 * g + 3] * inv) << 16);
      *(unsigned*)(orow + d0) = u0;
      *(unsigned*)(orow + d0 + 2) = u1;
      unsigned u2 = (unsigned)f2bf(accT1[4 * g + 0] * inv) | ((unsigned)f2bf(accT1[4 * g + 1] * inv) << 16);
      unsigned u3 = (unsigned)f2bf(accT1[4 * g + 2] * inv) | ((unsigned)f2bf(accT1[4 * g + 3] * inv) << 16);
      *(unsigned*)(orow + 32 + d0) = u2;
      *(unsigned*)(orow + 32 + d0 + 2) = u3;
    }
    __syncthreads();  // LDS/task_s safe before next pop
  }
}

// ---------------- launcher ----------------

extern "C" void kernel_launch(void* const* d_in, const int* in_sizes, int n_in,
                              void* d_out, int out_size, void* d_ws, size_t ws_size,
                              hipStream_t stream) {
  const float* x     = (const float*)d_in[0];
  const float* Wqkv  = (const float*)d_in[1];
  const float* Wproj = (const float*)d_in[2];
  const float* bproj = (const float*)d_in[3];
  float* out = (float*)d_out;

  char* ws = (char*)d_ws;
  unsigned short* xbf   = (unsigned short*)(ws);
  unsigned short* wqkvt = (unsigned short*)(ws + 12582912);
  unsigned short* wprjt = (unsigned short*)(ws + 16121856);
  unsigned short* Qb    = (unsigned short*)(ws + 17301504);
  unsigned short* Kb    = (unsigned short*)(ws + 29884416);
  unsigned short* Vtb   = (unsigned short*)(ws + 42467328);
  unsigned*       cnt   = (unsigned*)(ws + 55050240);

  cast_bf16_k<<<6144, 256, 0, stream>>>(x, xbf, (B_ * T_ * C_) / 4);
  tcast_bf16_k<<<(C_ * 3 * C_) / 256, 256, 0, stream>>>(Wqkv, wqkvt, C_, 3 * C_, cnt);
  tcast_bf16_k<<<(C_ * C_) / 256, 256, 0, stream>>>(Wproj, wprjt, C_, C_, nullptr);

  gemm_k<0><<<dim3((B_ * T_) / 128, (3 * C_) / 128), 256, 0, stream>>>(
      xbf, wqkvt, C_, Qb, Kb, Vtb, nullptr, nullptr);

  flash3_k<<<512, 256, 0, stream>>>(Qb, Kb, Vtb, xbf, cnt);

  gemm_k<1><<<dim3((B_ * T_) / 128, C_ / 128), 256, 0, stream>>>(
      xbf, wprjt, C_, nullptr, nullptr, nullptr, out, bproj);
}

// Round 4
// 231.273 us; speedup vs baseline: 2.3481x; 1.0034x over previous
//
#include <hip/hip_runtime.h>

#define B_ 2
#define T_ 4096
#define C_ 768
#define H_ 12
#define D_ 64
#define NTASK 768      /* 24 bh * 32 q-tiles of 128 */
#define QTASK 96       /* tasks per XCD queue: 3 bh * 32 qi */

typedef __attribute__((ext_vector_type(8))) short bf16x8;
typedef __attribute__((ext_vector_type(4))) float f32x4;
typedef __attribute__((ext_vector_type(16))) float f32x16;

__device__ __forceinline__ unsigned short f2bf(float f) {
  union { float f; unsigned u; } v; v.f = f;
  unsigned r = v.u + 0x7fffu + ((v.u >> 16) & 1u);
  return (unsigned short)(r >> 16);
}

__device__ __forceinline__ float exp2_hw(float x) {
  float r;
  asm("v_exp_f32 %0, %1" : "=v"(r) : "v"(x));
  return r;
}

__device__ __forceinline__ void gll16(const void* g, void* l) {
  __builtin_amdgcn_global_load_lds((const __attribute__((address_space(1))) void*)g,
                                   (__attribute__((address_space(3))) void*)l, 16, 0, 0);
}

// ---------------- cast kernels ----------------

__global__ __launch_bounds__(256) void cast_bf16_k(const float* __restrict__ in,
                                                   unsigned short* __restrict__ out, int n4) {
  int i = blockIdx.x * 256 + threadIdx.x;
  if (i >= n4) return;
  float4 v = ((const float4*)in)[i];
  union { unsigned short s[4]; unsigned long long u; } o;
  o.s[0] = f2bf(v.x); o.s[1] = f2bf(v.y); o.s[2] = f2bf(v.z); o.s[3] = f2bf(v.w);
  ((unsigned long long*)out)[i] = o.u;
}

// in [R][C] f32 -> out [C][R] bf16; optionally resets the task counters
__global__ __launch_bounds__(256) void tcast_bf16_k(const float* __restrict__ in,
                                                    unsigned short* __restrict__ out,
                                                    int R, int C, unsigned* cnt) {
  int idx = blockIdx.x * 256 + threadIdx.x;
  if (cnt != nullptr && idx < 128) cnt[idx] = 0u;
  if (idx >= R * C) return;
  int r = idx / C, c = idx - r * C;
  out[(size_t)c * R + r] = f2bf(in[idx]);
}

// ---------------- GEMM: A[M][K] bf16 row-major, Bt[N][K] bf16 row-major ----------------

#define QSCALE 0.1803368801111243f /* 0.125 * log2(e) */

template <int MODE>
__global__ __launch_bounds__(256) void gemm_k(const unsigned short* __restrict__ A,
                                              const unsigned short* __restrict__ Bt,
                                              int K,
                                              unsigned short* __restrict__ q_out,
                                              unsigned short* __restrict__ k_out,
                                              unsigned short* __restrict__ vt_out,
                                              float* __restrict__ f_out,
                                              const float* __restrict__ bias) {
  __shared__ short a_lds[128 * 32];
  __shared__ short b_lds[128 * 32];
  const int tid = threadIdx.x;
  const int wave = tid >> 6, lane = tid & 63;
  const int wm = wave >> 1, wn = wave & 1;
  const int lr = lane & 15, lc = lane >> 4;
  const int m0 = blockIdx.x * 128, n0 = blockIdx.y * 128;

  f32x4 acc[4][4];
  for (int mi = 0; mi < 4; ++mi)
    for (int ni = 0; ni < 4; ++ni) acc[mi][ni] = (f32x4){0.f, 0.f, 0.f, 0.f};

  for (int k0 = 0; k0 < K; k0 += 32) {
    __syncthreads();
    for (int p = 0; p < 2; ++p) {
      int chunk = p * 256 + wave * 64 + lane;
      int r = chunk >> 2, cc = chunk & 3;
      int c = cc ^ ((r >> 1) & 3);
      int base = (p * 256 + wave * 64) * 8;
      gll16(A + (size_t)(m0 + r) * K + k0 + c * 8, a_lds + base);
      gll16(Bt + (size_t)(n0 + r) * K + k0 + c * 8, b_lds + base);
    }
    __syncthreads();
    bf16x8 af[4], bfrag[4];
    for (int mi = 0; mi < 4; ++mi) {
      int r = wm * 64 + mi * 16 + lr;
      af[mi] = *(const bf16x8*)&a_lds[r * 32 + (lc ^ ((r >> 1) & 3)) * 8];
    }
    for (int ni = 0; ni < 4; ++ni) {
      int r = wn * 64 + ni * 16 + lr;
      bfrag[ni] = *(const bf16x8*)&b_lds[r * 32 + (lc ^ ((r >> 1) & 3)) * 8];
    }
    for (int mi = 0; mi < 4; ++mi)
      for (int ni = 0; ni < 4; ++ni)
        acc[mi][ni] = __builtin_amdgcn_mfma_f32_16x16x32_bf16(af[mi], bfrag[ni], acc[mi][ni], 0, 0, 0);
  }

  if (MODE == 0) {
    for (int mi = 0; mi < 4; ++mi)
      for (int ni = 0; ni < 4; ++ni) {
        int nn = n0 + wn * 64 + ni * 16 + lr;
        int which = nn / 768;
        int rem = nn - which * 768;
        int h = rem >> 6, d = rem & 63;
        for (int r = 0; r < 4; ++r) {
          int m = m0 + wm * 64 + mi * 16 + lc * 4 + r;
          int b = m >> 12, t = m & (T_ - 1);
          float av = acc[mi][ni][r];
          if (which == 0) av *= QSCALE;
          unsigned short val = f2bf(av);
          size_t bh = (size_t)(b * H_ + h);
          if (which == 0)      q_out[(bh * T_ + t) * D_ + d] = val;
          else if (which == 1) k_out[(bh * T_ + t) * D_ + d] = val;
          else                 vt_out[(bh * D_ + d) * T_ + t] = val;
        }
      }
  } else {
    for (int mi = 0; mi < 4; ++mi)
      for (int ni = 0; ni < 4; ++ni) {
        int nn = n0 + wn * 64 + ni * 16 + lr;
        float bv = bias[nn];
        for (int r = 0; r < 4; ++r) {
          int m = m0 + wm * 64 + mi * 16 + lc * 4 + r;
          f_out[(size_t)m * C_ + nn] = acc[mi][ni][r] + bv;
        }
      }
  }
}

// ---------------- flash attention v4 ----------------
// Per-XCD task queues (LPT over 3 bh each) + counted-vmcnt double-buffer pipeline.
// 768 blocks, 4 waves. Task = (bh, qi): 128 q rows, wave owns 32. KV tile = 64.
// LDS frag-linear: frag f is 1KB at f*512 shorts, read at base+lane*16B (conflict-free).
// Loop: { barrier0 (buf reuse guard); stage(it+1); vmcnt(4) [stage(it) landed,
//         stage(it+1) stays in flight]; barrier1; compute(it) }.

#define PACK8(SV, O)                                                              \
  do {                                                                            \
    unsigned w0, w1, w2, w3, w4, w5, w6, w7;                                      \
    asm("v_cvt_pk_bf16_f32 %0, %1, %2" : "=v"(w0) : "v"(SV[0]), "v"(SV[1]));      \
    asm("v_cvt_pk_bf16_f32 %0, %1, %2" : "=v"(w1) : "v"(SV[2]), "v"(SV[3]));      \
    asm("v_cvt_pk_bf16_f32 %0, %1, %2" : "=v"(w2) : "v"(SV[4]), "v"(SV[5]));      \
    asm("v_cvt_pk_bf16_f32 %0, %1, %2" : "=v"(w3) : "v"(SV[6]), "v"(SV[7]));      \
    asm("v_cvt_pk_bf16_f32 %0, %1, %2" : "=v"(w4) : "v"(SV[8]), "v"(SV[9]));      \
    asm("v_cvt_pk_bf16_f32 %0, %1, %2" : "=v"(w5) : "v"(SV[10]), "v"(SV[11]));    \
    asm("v_cvt_pk_bf16_f32 %0, %1, %2" : "=v"(w6) : "v"(SV[12]), "v"(SV[13]));    \
    asm("v_cvt_pk_bf16_f32 %0, %1, %2" : "=v"(w7) : "v"(SV[14]), "v"(SV[15]));    \
    asm("v_permlane32_swap_b32 %0, %1" : "+v"(w0), "+v"(w2));                     \
    asm("v_permlane32_swap_b32 %0, %1" : "+v"(w1), "+v"(w3));                     \
    asm("v_permlane32_swap_b32 %0, %1" : "+v"(w4), "+v"(w6));                     \
    asm("v_permlane32_swap_b32 %0, %1" : "+v"(w5), "+v"(w7));                     \
    pw[(O) + 0] = w0; pw[(O) + 1] = w1; pw[(O) + 2] = w2; pw[(O) + 3] = w3;       \
    pw[(O) + 4] = w4; pw[(O) + 5] = w5; pw[(O) + 6] = w6; pw[(O) + 7] = w7;       \
  } while (0)

__global__ __launch_bounds__(256) void flash4_k(const unsigned short* __restrict__ Qg,
                                                const unsigned short* __restrict__ Kg,
                                                const unsigned short* __restrict__ Vtg,
                                                unsigned short* __restrict__ Og,
                                                unsigned* __restrict__ cnt) {
  __shared__ short k_lds[2][8 * 512];
  __shared__ short vt_lds[2][8 * 512];
  __shared__ int task_s;

  const int tid = threadIdx.x;
  const int wave = tid >> 6, lane = tid & 63;
  const int lq = lane & 31;
  const int xq = blockIdx.x & 7;            // XCD-affine queue (heuristic)
  unsigned* myq = cnt + xq * 16;            // 64B-strided counters

  for (;;) {
    if (tid == 0) task_s = (int)atomicAdd(myq, 1u);
    __syncthreads();                        // broadcast + full vmcnt drain
    const int task = task_s;
    if (task >= QTASK) return;

    const int qi = 31 - task / 3;           // LPT: heavy first, 3 bh interleaved
    const int bh = xq * 3 + (task - (task / 3) * 3);
    const int qw = qi * 128 + wave * 32;
    const int q_g = qw + lq;

    const size_t kbase = (size_t)bh * T_ * D_;
    const size_t vbase = (size_t)bh * D_ * T_;

    // Q B-frags (pre-scaled by 0.125*log2e in GEMM1)
    const unsigned short* qrow = Qg + kbase + (size_t)q_g * D_;
    bf16x8 qf[4];
#pragma unroll
    for (int t = 0; t < 4; ++t) qf[t] = *(const bf16x8*)(qrow + t * 16 + (lane >> 5) * 8);

    f32x16 accT0, accT1;
#pragma unroll
    for (int r = 0; r < 16; ++r) { accT0[r] = 0.f; accT1[r] = 0.f; }
    float m = -INFINITY, l = 0.f;

    const int nt = 2 * qi + 2;

    auto stage = [&](int it, int buf) {
      const int kv = it * 64;
#pragma unroll
      for (int p = 0; p < 2; ++p) {
        int f = p * 4 + wave;
        int th = f >> 1, hf = f & 1;
        gll16(Kg + kbase + (size_t)(kv + hf * 32 + lq) * D_ + th * 16 + (lane >> 5) * 8,
              &k_lds[buf][f * 512]);
        gll16(Vtg + vbase + (size_t)(hf * 32 + lq) * T_ + kv + th * 16 + (lane >> 5) * 8,
              &vt_lds[buf][f * 512]);
      }
    };

    stage(0, 0);                            // 4 vm-ops/wave in flight

    for (int it = 0; it < nt; ++it) {
      const int kv = it * 64;
      const int buf = it & 1;

      __builtin_amdgcn_s_barrier();         // all waves done reading buf (it+1)&1
      __builtin_amdgcn_sched_barrier(0);
      if (it + 1 < nt) {
        stage(it + 1, buf ^ 1);
        asm volatile("s_waitcnt vmcnt(4)" ::: "memory");  // stage(it) landed
      } else {
        asm volatile("s_waitcnt vmcnt(0)" ::: "memory");
      }
      __builtin_amdgcn_sched_barrier(0);
      __builtin_amdgcn_s_barrier();         // buf[it&1] ready for everyone
      __builtin_amdgcn_sched_barrier(0);

      if (kv <= qw + 31) {
        // ---- S^T = K Q^T ----
        f32x16 s0, s1;
#pragma unroll
        for (int r = 0; r < 16; ++r) { s0[r] = 0.f; s1[r] = 0.f; }
        __builtin_amdgcn_s_setprio(1);
#pragma unroll
        for (int t = 0; t < 4; ++t) {
          bf16x8 kf0 = *(const bf16x8*)&k_lds[buf][(t * 2 + 0) * 512 + lane * 8];
          bf16x8 kf1 = *(const bf16x8*)&k_lds[buf][(t * 2 + 1) * 512 + lane * 8];
          s0 = __builtin_amdgcn_mfma_f32_32x32x16_bf16(kf0, qf[t], s0, 0, 0, 0);
          s1 = __builtin_amdgcn_mfma_f32_32x32x16_bf16(kf1, qf[t], s1, 0, 0, 0);
        }
        __builtin_amdgcn_s_setprio(0);

        const int hi = lane >> 5;
        // ---- causal mask (diagonal tiles only) ----
        if (kv + 63 > qw) {
#pragma unroll
          for (int r = 0; r < 16; ++r) {
            int key0 = kv + ((r & 3) + 8 * (r >> 2) + 4 * hi);
            if (key0 > q_g) s0[r] = -INFINITY;
            if (key0 + 32 > q_g) s1[r] = -INFINITY;
          }
        }

        // ---- online softmax (log2 domain, defer-max, tree reductions) ----
        float mx[16];
#pragma unroll
        for (int r = 0; r < 16; ++r) mx[r] = fmaxf(s0[r], s1[r]);
#pragma unroll
        for (int st = 8; st >= 1; st >>= 1)
#pragma unroll
          for (int r = 0; r < 8; ++r) {
            if (r < st) mx[r] = fmaxf(mx[r], mx[r + st]);
          }
        float rx = fmaxf(mx[0], __shfl_xor(mx[0], 32));
        if (!__all(rx <= m + 8.f)) {
          float mn = fmaxf(m, rx);
          float al = exp2_hw(m - mn);
          m = mn;
          l *= al;
#pragma unroll
          for (int r = 0; r < 16; ++r) { accT0[r] *= al; accT1[r] *= al; }
        }
#pragma unroll
        for (int r = 0; r < 16; ++r) s0[r] = exp2_hw(s0[r] - m);
#pragma unroll
        for (int r = 0; r < 16; ++r) s1[r] = exp2_hw(s1[r] - m);
        float sm[16];
#pragma unroll
        for (int r = 0; r < 16; ++r) sm[r] = s0[r] + s1[r];
#pragma unroll
        for (int st = 8; st >= 1; st >>= 1)
#pragma unroll
          for (int r = 0; r < 8; ++r) {
            if (r < st) sm[r] += sm[r + st];
          }
        l += sm[0] + __shfl_xor(sm[0], 32);

        // ---- P^T -> bf16 B-frags ----
        unsigned pw[16];
        PACK8(s0, 0);
        PACK8(s1, 8);

        // ---- O^T += Vt P^T ----
        __builtin_amdgcn_s_setprio(1);
#pragma unroll
        for (int ks = 0; ks < 4; ++ks) {
          union { unsigned u[4]; bf16x8 v; } pb;
          pb.u[0] = pw[ks * 4 + 0]; pb.u[1] = pw[ks * 4 + 1];
          pb.u[2] = pw[ks * 4 + 2]; pb.u[3] = pw[ks * 4 + 3];
          bf16x8 vf0 = *(const bf16x8*)&vt_lds[buf][(ks * 2 + 0) * 512 + lane * 8];
          bf16x8 vf1 = *(const bf16x8*)&vt_lds[buf][(ks * 2 + 1) * 512 + lane * 8];
          accT0 = __builtin_amdgcn_mfma_f32_32x32x16_bf16(vf0, pb.v, accT0, 0, 0, 0);
          accT1 = __builtin_amdgcn_mfma_f32_32x32x16_bf16(vf1, pb.v, accT1, 0, 0, 0);
        }
        __builtin_amdgcn_s_setprio(0);
      }
    }

    // ---- epilogue (cvt_pk + dwordx2 stores) ----
    const float inv = 1.0f / l;
    const int b = bh / H_, h = bh - b * H_;
    const int hi = lane >> 5;
    unsigned short* orow = Og + ((size_t)b * T_ + q_g) * C_ + h * D_;
#pragma unroll
    for (int g = 0; g < 4; ++g) {
      int d0 = 8 * g + 4 * hi;
      float a0 = accT0[4 * g + 0] * inv, a1 = accT0[4 * g + 1] * inv;
      float a2 = accT0[4 * g + 2] * inv, a3 = accT0[4 * g + 3] * inv;
      float b0 = accT1[4 * g + 0] * inv, b1 = accT1[4 * g + 1] * inv;
      float b2 = accT1[4 * g + 2] * inv, b3 = accT1[4 * g + 3] * inv;
      uint2 ua, ub;
      asm("v_cvt_pk_bf16_f32 %0, %1, %2" : "=v"(ua.x) : "v"(a0), "v"(a1));
      asm("v_cvt_pk_bf16_f32 %0, %1, %2" : "=v"(ua.y) : "v"(a2), "v"(a3));
      asm("v_cvt_pk_bf16_f32 %0, %1, %2" : "=v"(ub.x) : "v"(b0), "v"(b1));
      asm("v_cvt_pk_bf16_f32 %0, %1, %2" : "=v"(ub.y) : "v"(b2), "v"(b3));
      *(uint2*)(orow + d0) = ua;
      *(uint2*)(orow + 32 + d0) = ub;
    }
    __syncthreads();                        // quiesce before next pop reuses LDS
  }
}

// ---------------- launcher ----------------

extern "C" void kernel_launch(void* const* d_in, const int* in_sizes, int n_in,
                              void* d_out, int out_size, void* d_ws, size_t ws_size,
                              hipStream_t stream) {
  const float* x     = (const float*)d_in[0];
  const float* Wqkv  = (const float*)d_in[1];
  const float* Wproj = (const float*)d_in[2];
  const float* bproj = (const float*)d_in[3];
  float* out = (float*)d_out;

  char* ws = (char*)d_ws;
  unsigned short* xbf   = (unsigned short*)(ws);
  unsigned short* wqkvt = (unsigned short*)(ws + 12582912);
  unsigned short* wprjt = (unsigned short*)(ws + 16121856);
  unsigned short* Qb    = (unsigned short*)(ws + 17301504);
  unsigned short* Kb    = (unsigned short*)(ws + 29884416);
  unsigned short* Vtb   = (unsigned short*)(ws + 42467328);
  unsigned*       cnt   = (unsigned*)(ws + 55050240);  // 128 u32 (8 queues, 64B stride)

  cast_bf16_k<<<6144, 256, 0, stream>>>(x, xbf, (B_ * T_ * C_) / 4);
  tcast_bf16_k<<<(C_ * 3 * C_) / 256, 256, 0, stream>>>(Wqkv, wqkvt, C_, 3 * C_, cnt);
  tcast_bf16_k<<<(C_ * C_) / 256, 256, 0, stream>>>(Wproj, wprjt, C_, C_, nullptr);

  gemm_k<0><<<dim3((B_ * T_) / 128, (3 * C_) / 128), 256, 0, stream>>>(
      xbf, wqkvt, C_, Qb, Kb, Vtb, nullptr, nullptr);

  flash4_k<<<768, 256, 0, stream>>>(Qb, Kb, Vtb, xbf, cnt);

  gemm_k<1><<<dim3((B_ * T_) / 128, C_ / 128), 256, 0, stream>>>(
      xbf, wprjt, C_, nullptr, nullptr, nullptr, out, bproj);
}

// Round 5
// 197.464 us; speedup vs baseline: 2.7502x; 1.1712x over previous
//
#include <hip/hip_runtime.h>

#define B_ 2
#define T_ 4096
#define C_ 768
#define H_ 12
#define D_ 64
#define QTASK 96       /* tasks per XCD queue: 3 bh * 32 qi */

typedef __attribute__((ext_vector_type(8))) short bf16x8;
typedef __attribute__((ext_vector_type(4))) float f32x4;
typedef __attribute__((ext_vector_type(16))) float f32x16;

__device__ __forceinline__ unsigned short f2bf(float f) {
  union { float f; unsigned u; } v; v.f = f;
  unsigned r = v.u + 0x7fffu + ((v.u >> 16) & 1u);
  return (unsigned short)(r >> 16);
}

__device__ __forceinline__ float exp2_hw(float x) {
  float r;
  asm("v_exp_f32 %0, %1" : "=v"(r) : "v"(x));
  return r;
}

__device__ __forceinline__ void gll16(const void* g, void* l) {
  __builtin_amdgcn_global_load_lds((const __attribute__((address_space(1))) void*)g,
                                   (__attribute__((address_space(3))) void*)l, 16, 0, 0);
}

// ---------------- cast kernels ----------------

// f32 -> bf16 (coalesced), also resets the 8 task-queue counters
__global__ __launch_bounds__(256) void cast_bf16_k(const float* __restrict__ in,
                                                   unsigned short* __restrict__ out, int n4,
                                                   unsigned* __restrict__ cnt) {
  int i = blockIdx.x * 256 + threadIdx.x;
  if (i < 128) cnt[i] = 0u;
  if (i >= n4) return;
  float4 v = ((const float4*)in)[i];
  union { unsigned short s[4]; unsigned long long u; } o;
  o.s[0] = f2bf(v.x); o.s[1] = f2bf(v.y); o.s[2] = f2bf(v.z); o.s[3] = f2bf(v.w);
  ((unsigned long long*)out)[i] = o.u;
}

// in [R][C] f32 -> out [C][R] bf16, 64x64 tiles via LDS (coalesced both sides)
__global__ __launch_bounds__(256) void tpose_cast_k(const float* __restrict__ in,
                                                    unsigned short* __restrict__ out,
                                                    int R, int C) {
  __shared__ unsigned short t[64][65];
  const int c0 = blockIdx.x * 64, r0 = blockIdx.y * 64;
  const int tr = threadIdx.x >> 6, tc = threadIdx.x & 63;
#pragma unroll
  for (int i = 0; i < 16; ++i) {
    int r = i * 4 + tr;
    t[r][tc] = f2bf(in[(size_t)(r0 + r) * C + c0 + tc]);
  }
  __syncthreads();
#pragma unroll
  for (int i = 0; i < 16; ++i) {
    int c = i * 4 + tr;
    out[(size_t)(c0 + c) * R + r0 + tc] = t[tc][c];
  }
}

// ---------------- GEMM: A[M][K] bf16 row-major, Bt[N][K] bf16 row-major ----------------
// 128x128 tile, BK=32, 4 waves (2x2), double-buffered LDS + counted-vmcnt pipeline.
// XCD-contiguous remap: each XCD owns 8 M-panels (1.6 MB, L2-resident).
// MODE 0: scatter into Q(scaled)/K/Vt. MODE 1: f32 out + bias.

#define QSCALE 0.1803368801111243f /* 0.125 * log2(e) */

template <int MODE>
__global__ __launch_bounds__(256) void gemm_k(const unsigned short* __restrict__ A,
                                              const unsigned short* __restrict__ Bt,
                                              int K,
                                              unsigned short* __restrict__ q_out,
                                              unsigned short* __restrict__ k_out,
                                              unsigned short* __restrict__ vt_out,
                                              float* __restrict__ f_out,
                                              const float* __restrict__ bias) {
  __shared__ short a_lds[2][128 * 32];
  __shared__ short b_lds[2][128 * 32];
  const int tid = threadIdx.x;
  const int wave = tid >> 6, lane = tid & 63;
  const int wm = wave >> 1, wn = wave & 1;
  const int lr = lane & 15, lc = lane >> 4;

  const int id = blockIdx.x;
  const int xcd = id & 7, idc = id >> 3;
  const int bx = xcd * 8 + (idc & 7);
  const int by = idc >> 3;
  const int m0 = bx * 128, n0 = by * 128;

  f32x4 acc[4][4];
  for (int mi = 0; mi < 4; ++mi)
    for (int ni = 0; ni < 4; ++ni) acc[mi][ni] = (f32x4){0.f, 0.f, 0.f, 0.f};

  // staging pointers (chunk = p*256 + wave*64 + lane; r=chunk>>2, cc=chunk&3)
  const unsigned short *ap[2], *bp[2];
  int lb[2];
#pragma unroll
  for (int p = 0; p < 2; ++p) {
    int chunk = p * 256 + wave * 64 + lane;
    int r = chunk >> 2, cc = chunk & 3;
    int c = cc ^ ((r >> 1) & 3);
    ap[p] = A + (size_t)(m0 + r) * K + c * 8;
    bp[p] = Bt + (size_t)(n0 + r) * K + c * 8;
    lb[p] = (p * 256 + wave * 64) * 8;
  }

  const int nks = K >> 5;
  // stage(0)
#pragma unroll
  for (int p = 0; p < 2; ++p) {
    gll16(ap[p], &a_lds[0][lb[p]]);
    gll16(bp[p], &b_lds[0][lb[p]]);
    ap[p] += 32; bp[p] += 32;
  }

  for (int ks = 0; ks < nks; ++ks) {
    const int buf = ks & 1;
    __builtin_amdgcn_s_barrier();
    __builtin_amdgcn_sched_barrier(0);
    if (ks + 1 < nks) {
#pragma unroll
      for (int p = 0; p < 2; ++p) {
        gll16(ap[p], &a_lds[buf ^ 1][lb[p]]);
        gll16(bp[p], &b_lds[buf ^ 1][lb[p]]);
        ap[p] += 32; bp[p] += 32;
      }
      asm volatile("s_waitcnt vmcnt(4)" ::: "memory");
    } else {
      asm volatile("s_waitcnt vmcnt(0)" ::: "memory");
    }
    __builtin_amdgcn_sched_barrier(0);
    __builtin_amdgcn_s_barrier();
    __builtin_amdgcn_sched_barrier(0);

    bf16x8 af[4], bfrag[4];
#pragma unroll
    for (int mi = 0; mi < 4; ++mi) {
      int r = wm * 64 + mi * 16 + lr;
      af[mi] = *(const bf16x8*)&a_lds[buf][r * 32 + (lc ^ ((r >> 1) & 3)) * 8];
    }
#pragma unroll
    for (int ni = 0; ni < 4; ++ni) {
      int r = wn * 64 + ni * 16 + lr;
      bfrag[ni] = *(const bf16x8*)&b_lds[buf][r * 32 + (lc ^ ((r >> 1) & 3)) * 8];
    }
    __builtin_amdgcn_s_setprio(1);
#pragma unroll
    for (int mi = 0; mi < 4; ++mi)
#pragma unroll
      for (int ni = 0; ni < 4; ++ni)
        acc[mi][ni] = __builtin_amdgcn_mfma_f32_16x16x32_bf16(af[mi], bfrag[ni], acc[mi][ni], 0, 0, 0);
    __builtin_amdgcn_s_setprio(0);
  }

  if (MODE == 0) {
    const int nn0 = n0 + wn * 64 + lr;
    const int which = n0 / 768;  // uniform per block
#pragma unroll
    for (int mi = 0; mi < 4; ++mi)
#pragma unroll
      for (int ni = 0; ni < 4; ++ni) {
        int nn = nn0 + ni * 16;
        int rem = nn - which * 768;
        int h = rem >> 6, d = rem & 63;
        int t0v = m0 + wm * 64 + mi * 16 + lc * 4;
        int b = t0v >> 12, t = t0v & (T_ - 1);
        size_t bh = (size_t)(b * H_ + h);
        if (which == 2) {
          // Vt: t consecutive over r -> pack 4 bf16 -> 8B store
          unsigned u0, u1;
          asm("v_cvt_pk_bf16_f32 %0, %1, %2" : "=v"(u0) : "v"(acc[mi][ni][0]), "v"(acc[mi][ni][1]));
          asm("v_cvt_pk_bf16_f32 %0, %1, %2" : "=v"(u1) : "v"(acc[mi][ni][2]), "v"(acc[mi][ni][3]));
          uint2 u = {u0, u1};
          *(uint2*)&vt_out[(bh * D_ + d) * T_ + t] = u;
        } else {
#pragma unroll
          for (int r = 0; r < 4; ++r) {
            float av = acc[mi][ni][r];
            if (which == 0) av *= QSCALE;
            unsigned short val = f2bf(av);
            if (which == 0) q_out[(bh * T_ + t + r) * D_ + d] = val;
            else            k_out[(bh * T_ + t + r) * D_ + d] = val;
          }
        }
      }
  } else {
#pragma unroll
    for (int mi = 0; mi < 4; ++mi)
#pragma unroll
      for (int ni = 0; ni < 4; ++ni) {
        int nn = n0 + wn * 64 + ni * 16 + lr;
        float bv = bias[nn];
#pragma unroll
        for (int r = 0; r < 4; ++r) {
          int m = m0 + wm * 64 + mi * 16 + lc * 4 + r;
          f_out[(size_t)m * C_ + nn] = acc[mi][ni][r] + bv;
        }
      }
  }
}

// ---------------- flash attention v5 ----------------
// Per-XCD queues (LPT), 1024 blocks (4/CU), counted-vmcnt double buffer.
// Softmax: m folded into MFMA C-init (S = QK - m directly, m starts 0),
// l kept as 16-reg lvec (horizontal reduce once per task).

#define PACK8(SV, O)                                                              \
  do {                                                                            \
    unsigned w0, w1, w2, w3, w4, w5, w6, w7;                                      \
    asm("v_cvt_pk_bf16_f32 %0, %1, %2" : "=v"(w0) : "v"(SV[0]), "v"(SV[1]));      \
    asm("v_cvt_pk_bf16_f32 %0, %1, %2" : "=v"(w1) : "v"(SV[2]), "v"(SV[3]));      \
    asm("v_cvt_pk_bf16_f32 %0, %1, %2" : "=v"(w2) : "v"(SV[4]), "v"(SV[5]));      \
    asm("v_cvt_pk_bf16_f32 %0, %1, %2" : "=v"(w3) : "v"(SV[6]), "v"(SV[7]));      \
    asm("v_cvt_pk_bf16_f32 %0, %1, %2" : "=v"(w4) : "v"(SV[8]), "v"(SV[9]));      \
    asm("v_cvt_pk_bf16_f32 %0, %1, %2" : "=v"(w5) : "v"(SV[10]), "v"(SV[11]));    \
    asm("v_cvt_pk_bf16_f32 %0, %1, %2" : "=v"(w6) : "v"(SV[12]), "v"(SV[13]));    \
    asm("v_cvt_pk_bf16_f32 %0, %1, %2" : "=v"(w7) : "v"(SV[14]), "v"(SV[15]));    \
    asm("v_permlane32_swap_b32 %0, %1" : "+v"(w0), "+v"(w2));                     \
    asm("v_permlane32_swap_b32 %0, %1" : "+v"(w1), "+v"(w3));                     \
    asm("v_permlane32_swap_b32 %0, %1" : "+v"(w4), "+v"(w6));                     \
    asm("v_permlane32_swap_b32 %0, %1" : "+v"(w5), "+v"(w7));                     \
    pw[(O) + 0] = w0; pw[(O) + 1] = w1; pw[(O) + 2] = w2; pw[(O) + 3] = w3;       \
    pw[(O) + 4] = w4; pw[(O) + 5] = w5; pw[(O) + 6] = w6; pw[(O) + 7] = w7;       \
  } while (0)

__global__ __launch_bounds__(256) void flash5_k(const unsigned short* __restrict__ Qg,
                                                const unsigned short* __restrict__ Kg,
                                                const unsigned short* __restrict__ Vtg,
                                                unsigned short* __restrict__ Og,
                                                unsigned* __restrict__ cnt) {
  __shared__ short k_lds[2][8 * 512];
  __shared__ short vt_lds[2][8 * 512];
  __shared__ int task_s;

  const int tid = threadIdx.x;
  const int wave = tid >> 6, lane = tid & 63;
  const int lq = lane & 31, hi = lane >> 5;
  const int xq = blockIdx.x & 7;
  unsigned* myq = cnt + xq * 16;

  for (;;) {
    if (tid == 0) task_s = (int)atomicAdd(myq, 1u);
    __syncthreads();
    const int task = task_s;
    if (task >= QTASK) return;

    const int qi = 31 - task / 3;       // LPT: heavy first
    const int bh = xq * 3 + (task - (task / 3) * 3);
    const int qw = qi * 128 + wave * 32;
    const int q_g = qw + lq;

    const size_t kbase = (size_t)bh * T_ * D_;
    const size_t vbase = (size_t)bh * D_ * T_;

    const unsigned short* qrow = Qg + kbase + (size_t)q_g * D_;
    bf16x8 qf[4];
#pragma unroll
    for (int t = 0; t < 4; ++t) qf[t] = *(const bf16x8*)(qrow + t * 16 + hi * 8);

    f32x16 accT0, accT1;
#pragma unroll
    for (int r = 0; r < 16; ++r) { accT0[r] = 0.f; accT1[r] = 0.f; }
    float lvec[16];
#pragma unroll
    for (int r = 0; r < 16; ++r) lvec[r] = 0.f;
    float m = 0.f;  // safe: rescale triggers if any tile exceeds m+8

    const int nt = 2 * qi + 2;

    // hoisted stage pointers: frags f=wave and f=wave+4
    const unsigned short* kp = Kg + kbase + (size_t)((wave & 1) * 32 + lq) * D_ + (wave >> 1) * 16 + hi * 8;
    const unsigned short* vp = Vtg + vbase + (size_t)((wave & 1) * 32 + lq) * T_ + (wave >> 1) * 16 + hi * 8;
    const int lb0 = wave * 512, lb1 = (wave + 4) * 512;

    gll16(kp, &k_lds[0][lb0]); gll16(kp + 32, &k_lds[0][lb1]);
    gll16(vp, &vt_lds[0][lb0]); gll16(vp + 32, &vt_lds[0][lb1]);
    const unsigned short* kpn = kp + 64 * D_;
    const unsigned short* vpn = vp + 64;

    for (int it = 0; it < nt; ++it) {
      const int kv = it * 64;
      const int buf = it & 1;

      __builtin_amdgcn_s_barrier();
      __builtin_amdgcn_sched_barrier(0);
      if (it + 1 < nt) {
        gll16(kpn, &k_lds[buf ^ 1][lb0]); gll16(kpn + 32, &k_lds[buf ^ 1][lb1]);
        gll16(vpn, &vt_lds[buf ^ 1][lb0]); gll16(vpn + 32, &vt_lds[buf ^ 1][lb1]);
        kpn += 64 * D_; vpn += 64;
        asm volatile("s_waitcnt vmcnt(4)" ::: "memory");
      } else {
        asm volatile("s_waitcnt vmcnt(0)" ::: "memory");
      }
      __builtin_amdgcn_sched_barrier(0);
      __builtin_amdgcn_s_barrier();
      __builtin_amdgcn_sched_barrier(0);

      if (kv <= qw + 31) {
        // ---- S^T = K Q^T - m  (C-init = -m) ----
        const float negm = -m;
        f32x16 s0, s1;
#pragma unroll
        for (int r = 0; r < 16; ++r) { s0[r] = negm; s1[r] = negm; }
        __builtin_amdgcn_s_setprio(1);
#pragma unroll
        for (int t = 0; t < 4; ++t) {
          bf16x8 kf0 = *(const bf16x8*)&k_lds[buf][(t * 2 + 0) * 512 + lane * 8];
          bf16x8 kf1 = *(const bf16x8*)&k_lds[buf][(t * 2 + 1) * 512 + lane * 8];
          s0 = __builtin_amdgcn_mfma_f32_32x32x16_bf16(kf0, qf[t], s0, 0, 0, 0);
          s1 = __builtin_amdgcn_mfma_f32_32x32x16_bf16(kf1, qf[t], s1, 0, 0, 0);
        }
        __builtin_amdgcn_s_setprio(0);

        // ---- causal mask (diagonal tiles only) ----
        if (kv + 63 > qw) {
#pragma unroll
          for (int r = 0; r < 16; ++r) {
            int key0 = kv + ((r & 3) + 8 * (r >> 2) + 4 * hi);
            if (key0 > q_g) s0[r] = -INFINITY;
            if (key0 + 32 > q_g) s1[r] = -INFINITY;
          }
        }

        // ---- relative max (max3-friendly tree) ----
        float mx[16];
#pragma unroll
        for (int r = 0; r < 16; ++r) mx[r] = fmaxf(s0[r], s1[r]);
        float a0 = fmaxf(fmaxf(mx[0], mx[1]), mx[2]);
        float a1 = fmaxf(fmaxf(mx[3], mx[4]), mx[5]);
        float a2 = fmaxf(fmaxf(mx[6], mx[7]), mx[8]);
        float a3 = fmaxf(fmaxf(mx[9], mx[10]), mx[11]);
        float a4 = fmaxf(fmaxf(mx[12], mx[13]), mx[14]);
        float rx = fmaxf(fmaxf(fmaxf(a0, a1), fmaxf(a2, a3)), fmaxf(a4, mx[15]));
        rx = fmaxf(rx, __shfl_xor(rx, 32));

        if (!__all(rx <= 8.f)) {
          float dlt = fmaxf(rx, 0.f);
          float al = exp2_hw(-dlt);
          m += dlt;
#pragma unroll
          for (int r = 0; r < 16; ++r) { accT0[r] *= al; accT1[r] *= al; lvec[r] *= al; }
#pragma unroll
          for (int r = 0; r < 16; ++r) { s0[r] -= dlt; s1[r] -= dlt; }
        }
#pragma unroll
        for (int r = 0; r < 16; ++r) s0[r] = exp2_hw(s0[r]);
#pragma unroll
        for (int r = 0; r < 16; ++r) s1[r] = exp2_hw(s1[r]);
#pragma unroll
        for (int r = 0; r < 16; ++r) lvec[r] += s0[r] + s1[r];

        // ---- P^T -> bf16 B-frags ----
        unsigned pw[16];
        PACK8(s0, 0);
        PACK8(s1, 8);

        // ---- O^T += Vt P^T ----
        __builtin_amdgcn_s_setprio(1);
#pragma unroll
        for (int ks = 0; ks < 4; ++ks) {
          union { unsigned u[4]; bf16x8 v; } pb;
          pb.u[0] = pw[ks * 4 + 0]; pb.u[1] = pw[ks * 4 + 1];
          pb.u[2] = pw[ks * 4 + 2]; pb.u[3] = pw[ks * 4 + 3];
          bf16x8 vf0 = *(const bf16x8*)&vt_lds[buf][(ks * 2 + 0) * 512 + lane * 8];
          bf16x8 vf1 = *(const bf16x8*)&vt_lds[buf][(ks * 2 + 1) * 512 + lane * 8];
          accT0 = __builtin_amdgcn_mfma_f32_32x32x16_bf16(vf0, pb.v, accT0, 0, 0, 0);
          accT1 = __builtin_amdgcn_mfma_f32_32x32x16_bf16(vf1, pb.v, accT1, 0, 0, 0);
        }
        __builtin_amdgcn_s_setprio(0);
      }
    }

    // ---- final l reduce + epilogue ----
    float l = 0.f;
#pragma unroll
    for (int r = 0; r < 16; ++r) l += lvec[r];
    l += __shfl_xor(l, 32);
    const float inv = 1.0f / l;
    const int b = bh / H_, h = bh - b * H_;
    unsigned short* orow = Og + ((size_t)b * T_ + q_g) * C_ + h * D_;
#pragma unroll
    for (int g = 0; g < 4; ++g) {
      int d0 = 8 * g + 4 * hi;
      float e0 = accT0[4 * g + 0] * inv, e1 = accT0[4 * g + 1] * inv;
      float e2 = accT0[4 * g + 2] * inv, e3 = accT0[4 * g + 3] * inv;
      float f0 = accT1[4 * g + 0] * inv, f1 = accT1[4 * g + 1] * inv;
      float f2 = accT1[4 * g + 2] * inv, f3 = accT1[4 * g + 3] * inv;
      uint2 ua, ub;
      asm("v_cvt_pk_bf16_f32 %0, %1, %2" : "=v"(ua.x) : "v"(e0), "v"(e1));
      asm("v_cvt_pk_bf16_f32 %0, %1, %2" : "=v"(ua.y) : "v"(e2), "v"(e3));
      asm("v_cvt_pk_bf16_f32 %0, %1, %2" : "=v"(ub.x) : "v"(f0), "v"(f1));
      asm("v_cvt_pk_bf16_f32 %0, %1, %2" : "=v"(ub.y) : "v"(f2), "v"(f3));
      *(uint2*)(orow + d0) = ua;
      *(uint2*)(orow + 32 + d0) = ub;
    }
    __syncthreads();  // quiesce LDS before next pop
  }
}

// ---------------- launcher ----------------

extern "C" void kernel_launch(void* const* d_in, const int* in_sizes, int n_in,
                              void* d_out, int out_size, void* d_ws, size_t ws_size,
                              hipStream_t stream) {
  const float* x     = (const float*)d_in[0];
  const float* Wqkv  = (const float*)d_in[1];
  const float* Wproj = (const float*)d_in[2];
  const float* bproj = (const float*)d_in[3];
  float* out = (float*)d_out;

  char* ws = (char*)d_ws;
  unsigned short* xbf   = (unsigned short*)(ws);
  unsigned short* wqkvt = (unsigned short*)(ws + 12582912);
  unsigned short* wprjt = (unsigned short*)(ws + 16121856);
  unsigned short* Qb    = (unsigned short*)(ws + 17301504);
  unsigned short* Kb    = (unsigned short*)(ws + 29884416);
  unsigned short* Vtb   = (unsigned short*)(ws + 42467328);
  unsigned*       cnt   = (unsigned*)(ws + 55050240);  // 128 u32

  cast_bf16_k<<<6144, 256, 0, stream>>>(x, xbf, (B_ * T_ * C_) / 4, cnt);
  tpose_cast_k<<<dim3((3 * C_) / 64, C_ / 64), 256, 0, stream>>>(Wqkv, wqkvt, C_, 3 * C_);
  tpose_cast_k<<<dim3(C_ / 64, C_ / 64), 256, 0, stream>>>(Wproj, wprjt, C_, C_);

  gemm_k<0><<<(B_ * T_ / 128) * (3 * C_ / 128), 256, 0, stream>>>(
      xbf, wqkvt, C_, Qb, Kb, Vtb, nullptr, nullptr);

  flash5_k<<<1024, 256, 0, stream>>>(Qb, Kb, Vtb, xbf, cnt);

  gemm_k<1><<<(B_ * T_ / 128) * (C_ / 128), 256, 0, stream>>>(
      xbf, wprjt, C_, nullptr, nullptr, nullptr, out, bproj);
}